// Round 9
// baseline (352.591 us; speedup 1.0000x reference)
//
#include <hip/hip_runtime.h>
#include <stdint.h>
#include <stddef.h>

// ---------- problem constants ----------
constexpr int BATCH = 2;
constexpr int SEQ   = 2048;
constexpr int EMB   = 2048;   // DIM
constexpr int HEADS = 16;
constexpr int GQA   = 4;      // kv heads
constexpr int HDIM  = 128;
constexpr int NQKV  = 3072;   // 2048 Q + 512 K + 512 V
constexpr int VOFF  = 2560;   // column offset of V region in fused QKV
constexpr int MROWS = BATCH * SEQ;  // 4096

typedef _Float16 half8  __attribute__((ext_vector_type(8)));
typedef _Float16 half4v __attribute__((ext_vector_type(4)));
typedef float    floatx4 __attribute__((ext_vector_type(4)));

__device__ __forceinline__ void st_c(float* p, float v)    { *p = v; }
__device__ __forceinline__ void st_c(_Float16* p, float v) { *p = (_Float16)v; }

// async global->LDS, 16 B per lane, LDS dest = wave-uniform base + lane*16
__device__ __forceinline__ void gld16(const _Float16* g, _Float16* l) {
    __builtin_amdgcn_global_load_lds(
        (const __attribute__((address_space(1))) void*)g,
        (__attribute__((address_space(3))) void*)l, 16, 0, 0);
}

// ---------- 1. cast x (fp32 -> f16) ----------
__global__ void cast_x_kernel(const float* __restrict__ x, _Float16* __restrict__ xh) {
    int i = (blockIdx.x * 256 + threadIdx.x) * 4;
    float4 v = *(const float4*)(x + i);
    half4v h;
    h[0] = (_Float16)v.x; h[1] = (_Float16)v.y; h[2] = (_Float16)v.z; h[3] = (_Float16)v.w;
    *(half4v*)(xh + i) = h;
}

// ---------- 2a. transpose + cast (single source): out[C x R] = in[R x C]^T ----------
__global__ void transpose_cast(const float* __restrict__ in, _Float16* __restrict__ out,
                               int R, int C) {
    __shared__ float tile[32][33];
    int cb = blockIdx.x * 32, rb = blockIdx.y * 32;
    int tx = threadIdx.x, ty = threadIdx.y;    // 32 x 8
    #pragma unroll
    for (int j = 0; j < 32; j += 8)
        tile[ty + j][tx] = in[(size_t)(rb + ty + j) * C + (cb + tx)];
    __syncthreads();
    #pragma unroll
    for (int j = 0; j < 32; j += 8)
        out[(size_t)(cb + ty + j) * R + (rb + tx)] = (_Float16)tile[tx][ty + j];
}

// ---------- 2b. merged Wq/Wk/Wv transpose+cast into fused Wqkv[N=3072][K=2048] ----------
__global__ void transpose_cast_qkv(const float* __restrict__ Wq, const float* __restrict__ Wk,
                                   const float* __restrict__ Wv, _Float16* __restrict__ out) {
    __shared__ float tile[32][33];
    int cb = blockIdx.x * 32, rb = blockIdx.y * 32;   // cb: fused out-row 0..3071
    const float* src; int C, cl;
    if (cb < 2048)      { src = Wq; C = 2048; cl = cb; }
    else if (cb < 2560) { src = Wk; C = 512;  cl = cb - 2048; }
    else                { src = Wv; C = 512;  cl = cb - 2560; }
    int tx = threadIdx.x, ty = threadIdx.y;    // 32 x 8
    #pragma unroll
    for (int j = 0; j < 32; j += 8)
        tile[ty + j][tx] = src[(size_t)(rb + ty + j) * C + (cl + tx)];
    __syncthreads();
    #pragma unroll
    for (int j = 0; j < 32; j += 8)
        out[(size_t)(cb + ty + j) * EMB + (rb + tx)] = (_Float16)tile[tx][ty + j];
}

// ---------- 3. GEMM: C[M,N] = A[M,K] * Bt[N,K]^T  (f16 in, fp32 acc) ----------
// R6 schedule (gld16 double-buffer, one drain-barrier/K-step, linear LDS,
// T1 XCD rects) with HALVED N-TILE (128x64): the R7/R8 evidence says this
// kernel family is resident-block-limited (occupancy was grid-capped at
// 3 blocks/CU). 128x64 -> 2x the blocks: qkv 1536 (6/CU), out 1024 (4/CU).
// Per block: 4 waves (2Mx2N), per-wave 64x32 out, 3 gld16/thread/K-step,
// LDS 24KB (6 blocks = 144 <= 160KB). XCD rect width doubled in tiles so
// per-XCD column coverage (and FETCH ~43MB) is unchanged.
template <typename CT, bool ROPE, int RXW, int RYH>
__global__ __launch_bounds__(256) void gemm_bt(const _Float16* __restrict__ A,
                                               const _Float16* __restrict__ Bt,
                                               CT* __restrict__ C,
                                               int M, int N, int K,
                                               const float* __restrict__ fc,
                                               const float* __restrict__ fs) {
    __shared__ _Float16 As[2][128 * 32];
    __shared__ _Float16 Bs[2][64 * 32];
    const int tid  = threadIdx.x;
    // XCD rectangle remap (grid = (2*RXW) x (4*RYH), both divisible by 8)
    const int bid = blockIdx.y * (2 * RXW) + blockIdx.x;
    const int xcd = bid & 7, loc = bid >> 3;
    const int bxi = (xcd & 1) * RXW + (loc % RXW);
    const int byi = (xcd >> 1) * RYH + (loc / RXW);
    const int bm  = byi * 128, bn = bxi * 64;
    const int lane = tid & 63, wid = tid >> 6;
    const int wr   = wid >> 1, wc = wid & 1;
    const int qd   = lane >> 4, m15 = lane & 15;

    // staging: lane l -> row wid*16 + (l>>2), col (l&3)*8 (linear gld16 fill).
    // A: rows wid*16+srow and +64 (2 units). B: rows wid*16+srow (1 unit, 64 rows).
    const int srow = lane >> 2;
    const int scol = (lane & 3) * 8;
    const _Float16* Ag = A  + (size_t)(bm + wid * 16 + srow) * K + scol;
    const _Float16* Bg = Bt + (size_t)(bn + wid * 16 + srow) * K + scol;
    const size_t rowskip = (size_t)64 * K;
    const int woff = wid * 16 * 32;

    // prologue: stage tile 0 into buffer 0
    gld16(Ag,           &As[0][woff]);
    gld16(Ag + rowskip, &As[0][woff + 64 * 32]);
    gld16(Bg,           &Bs[0][woff]);

    floatx4 acc[4][2] = {};
    const int nk = K >> 5;   // K/32 tiles

    for (int kt = 0; kt < nk; ++kt) {
        const int cur = kt & 1;
        __syncthreads();   // buf[cur] staged (vmcnt drained); prev reads of buf[cur^1] done
        if (kt + 1 < nk) { // stage tile kt+1 into the other buffer
            const int ko = (kt + 1) * 32;
            gld16(Ag + ko,           &As[cur ^ 1][woff]);
            gld16(Ag + rowskip + ko, &As[cur ^ 1][woff + 64 * 32]);
            gld16(Bg + ko,           &Bs[cur ^ 1][woff]);
        }
        const _Float16* AsR = &As[cur][(wr * 64 + m15) * 32 + qd * 8];
        const _Float16* BsR = &Bs[cur][(wc * 32 + m15) * 32 + qd * 8];
        half8 af[4], bf[2];
        #pragma unroll
        for (int i = 0; i < 4; i++) af[i] = *(const half8*)(AsR + i * 16 * 32);
        #pragma unroll
        for (int i = 0; i < 2; i++) bf[i] = *(const half8*)(BsR + i * 16 * 32);
        #pragma unroll
        for (int mi = 0; mi < 4; mi++)
            #pragma unroll
            for (int ni = 0; ni < 2; ni++)
                acc[mi][ni] = __builtin_amdgcn_mfma_f32_16x16x32_f16(af[mi], bf[ni], acc[mi][ni], 0, 0, 0);
    }

    #pragma unroll
    for (int mi = 0; mi < 4; mi++)
        #pragma unroll
        for (int ni = 0; ni < 2; ni++)
            #pragma unroll
            for (int r = 0; r < 4; r++) {
                int row = bm + wr * 64 + mi * 16 + qd * 4 + r;
                int col = bn + wc * 32 + ni * 16 + m15;
                float v = acc[mi][ni][r];
                if (ROPE && col < VOFF) {
                    int si = row & (SEQ - 1);
                    int fi = (col >> 1) & 63;
                    float c  = fc[si * 64 + fi];
                    float sn = fs[si * 64 + fi];
                    float other = __shfl_xor(v, 1, 64);
                    v = (m15 & 1) ? (v * c + other * sn) : (v * c - other * sn);
                }
                st_c(&C[(size_t)row * N + col], v);
            }
}

// ---------- 4b. V -> Vt[b][g][d][s]  (d rows 0..127) ----------
__global__ void transpose_v(const _Float16* __restrict__ qkv, _Float16* __restrict__ vt) {
    __shared__ _Float16 tile[32][33];
    int sb = blockIdx.x * 32, db = blockIdx.y * 32;
    int bg = blockIdx.z;
    int tx = threadIdx.x, ty = threadIdx.y;
    const _Float16* src = qkv + (size_t)(bg >> 2) * SEQ * NQKV + VOFF + (bg & 3) * HDIM;
    #pragma unroll
    for (int j = 0; j < 32; j += 8)
        tile[ty + j][tx] = src[(size_t)(sb + ty + j) * NQKV + db + tx];
    __syncthreads();
    _Float16* dst = vt + (size_t)bg * HDIM * SEQ;
    #pragma unroll
    for (int j = 0; j < 32; j += 8)
        dst[(size_t)(db + ty + j) * SEQ + sb + tx] = tile[tx][ty + j];
}

// ---------- 5. flash attention: 4 waves (2 heads x 2 row-halves), paired q-tiles ----------
// R8 configuration (measured win: 2 blocks/CU). Unchanged.
__global__ __launch_bounds__(256, 2) void flash_attn(const _Float16* __restrict__ qkv,
                                                     const _Float16* __restrict__ vt,
                                                     _Float16* __restrict__ ob) {
    const int bx   = blockIdx.x;          // 0..31
    const int g    = blockIdx.y >> 1;     // kv group
    const int hp   = blockIdx.y & 1;      // head-pair within group
    const int b    = blockIdx.z;
    const int tid  = threadIdx.x;
    const int lane = tid & 63, wid = tid >> 6;   // 4 waves
    const int h    = g * 4 + hp * 2 + (wid & 1);
    const int su   = wid >> 1;                   // 16-row half of the 32-row tile
    const int qd   = lane >> 4, m15 = lane & 15;

    __shared__ _Float16 Ks[2][64 * 128];   // [key][d], swizzled 16B chunks
    __shared__ _Float16 Vs[2][128 * 64];   // [d][key], swizzled
    __shared__ _Float16 Ps[4][16 * 64];    // per-wave P slice, swizzled

    const _Float16* kg = qkv + (size_t)(b * SEQ) * NQKV + EMB + g * HDIM;
    const _Float16* vg = vt + (size_t)(b * GQA + g) * HDIM * SEQ;
    _Float16* pw = Ps[wid];

    // staging: K 64x128 = 16 wave-instrs, V 128x64 = 16; unit t = wid*4+j
    const int kl = lane >> 4, kc16 = lane & 15;
    const int vl = lane >> 3, vc8  = lane & 7;
    const _Float16* kgp[4]; const _Float16* vgp[4];
    int ksoff[4], vsoff[4];
    #pragma unroll
    for (int j = 0; j < 4; j++) {
        int t = wid * 4 + j;
        int kr = t * 4 + kl;
        kgp[j] = kg + (size_t)kr * NQKV + ((kc16 ^ (kr & 15)) * 8);
        ksoff[j] = t * 512;
        int vr = t * 8 + vl;
        vgp[j] = vg + (size_t)vr * SEQ + ((vc8 ^ (vr & 7)) * 8);
        vsoff[j] = t * 512;
    }

    half8 ones;
    #pragma unroll
    for (int i = 0; i < 8; i++) ones[i] = (_Float16)1.0f;
    // fold 1/sqrt(128) * log2(e) into Q so p = exp2(score)
    const _Float16 qsc = (_Float16)(0.08838834764831845f * 1.44269504088896341f);

    for (int ph = 0; ph < 2; ++ph) {
        const int sidx   = ph ? bx : 63 - bx;
        const int q0     = sidx * 32;
        const int ktLast = sidx >> 1;

        __syncthreads();   // all waves done reading buffers from previous phase
        #pragma unroll
        for (int j = 0; j < 4; j++) gld16(kgp[j], &Ks[0][ksoff[j]]);
        #pragma unroll
        for (int j = 0; j < 4; j++) gld16(vgp[j], &Vs[0][vsoff[j]]);

        // Q fragments (A-operand), pre-scaled; this wave's 16 rows
        half8 qf[4];
        {
            const _Float16* qb = qkv + (size_t)(b * SEQ + q0 + su * 16 + m15) * NQKV + h * HDIM + qd * 8;
            #pragma unroll
            for (int kc = 0; kc < 4; kc++) {
                half8 q = *(const half8*)(qb + kc * 32);
                #pragma unroll
                for (int i = 0; i < 8; i++) q[i] = (_Float16)(q[i] * qsc);
                qf[kc] = q;
            }
        }

        floatx4 o[9] = {};   // [0..7]=dims, [8]=denominator

        for (int kt = 0; kt <= ktLast; ++kt) {
            const int cur = kt & 1;
            __syncthreads();    // drains vmcnt -> tile kt staged; prev reads done
            if (kt < ktLast) {  // stage tile kt+1 into other buffer
                const int nb = cur ^ 1;
                const size_t ko = (size_t)(kt + 1) * 64;
                #pragma unroll
                for (int j = 0; j < 4; j++) gld16(kgp[j] + ko * NQKV, &Ks[nb][ksoff[j]]);
                #pragma unroll
                for (int j = 0; j < 4; j++) gld16(vgp[j] + ko, &Vs[nb][vsoff[j]]);
            }
            const _Float16* ksb = Ks[cur];
            const _Float16* vsb = Vs[cur];

            // S = Q K^T
            floatx4 sa[4] = {};
            __builtin_amdgcn_s_setprio(1);
            #pragma unroll
            for (int nt = 0; nt < 4; ++nt) {
                const int kr = nt * 16 + m15;
                #pragma unroll
                for (int kc = 0; kc < 4; ++kc) {
                    half8 kf = *(const half8*)(&ksb[kr * 128 + (((kc * 4 + qd) ^ (kr & 15)) * 8)]);
                    sa[nt] = __builtin_amdgcn_mfma_f32_16x16x32_f16(qf[kc], kf, sa[nt], 0, 0, 0);
                }
            }
            __builtin_amdgcn_s_setprio(0);

            // p = exp2(s); causal mask only on the diagonal tile; write to LDS
            const bool diag = (kt == ktLast);
            const int  k0   = kt * 64;
            #pragma unroll
            for (int r = 0; r < 4; r++) {
                const int prow = qd * 4 + r;                 // local row 0..15
                const int rowg = q0 + su * 16 + prow;        // global q row
                #pragma unroll
                for (int nt = 0; nt < 4; nt++) {
                    float p = __builtin_exp2f(sa[nt][r]);
                    if (diag && (k0 + nt * 16 + m15 > rowg)) p = 0.f;
                    int chunk = (nt * 2 + (m15 >> 3)) ^ (prow & 7);
                    pw[prow * 64 + chunk * 8 + (m15 & 7)] = (_Float16)p;
                }
            }

            // P fragments back (A-operand, wave-private in-order DS)
            half8 pf[2];
            #pragma unroll
            for (int kc = 0; kc < 2; kc++)
                pf[kc] = *(const half8*)(&pw[m15 * 64 + (((kc * 4 + qd) ^ (m15 & 7)) * 8)]);

            // O += P V ; denominator via ones fragment
            __builtin_amdgcn_s_setprio(1);
            #pragma unroll
            for (int dt = 0; dt < 8; dt++) {
                const int vr = dt * 16 + m15;
                #pragma unroll
                for (int kc = 0; kc < 2; kc++) {
                    half8 vf = *(const half8*)(&vsb[vr * 64 + (((kc * 4 + qd) ^ (vr & 7)) * 8)]);
                    o[dt] = __builtin_amdgcn_mfma_f32_16x16x32_f16(pf[kc], vf, o[dt], 0, 0, 0);
                }
            }
            o[8] = __builtin_amdgcn_mfma_f32_16x16x32_f16(pf[0], ones, o[8], 0, 0, 0);
            o[8] = __builtin_amdgcn_mfma_f32_16x16x32_f16(pf[1], ones, o[8], 0, 0, 0);
            __builtin_amdgcn_s_setprio(0);
        }

        // epilogue: every lane of a row-group holds the same l in o[8][r]
        float linv[4];
        #pragma unroll
        for (int r = 0; r < 4; r++) linv[r] = 1.0f / o[8][r];
        _Float16* od = ob + (size_t)(b * SEQ + q0 + su * 16) * EMB + h * HDIM;
        #pragma unroll
        for (int dt = 0; dt < 8; dt++)
            #pragma unroll
            for (int r = 0; r < 4; r++)
                od[(size_t)(qd * 4 + r) * EMB + dt * 16 + m15] = (_Float16)(o[dt][r] * linv[r]);
    }
}

// ---------- launcher ----------
extern "C" void kernel_launch(void* const* d_in, const int* in_sizes, int n_in,
                              void* d_out, int out_size, void* d_ws, size_t ws_size,
                              hipStream_t stream) {
    (void)in_sizes; (void)n_in; (void)out_size; (void)ws_size;
    const float* x  = (const float*)d_in[0];
    const float* fc = (const float*)d_in[1];
    const float* fs = (const float*)d_in[2];
    const float* Wq = (const float*)d_in[3];
    const float* Wk = (const float*)d_in[4];
    const float* Wv = (const float*)d_in[5];
    const float* Wo = (const float*)d_in[6];
    float* out = (float*)d_out;

    // workspace layout (f16), 60 MB
    _Float16* Xb   = (_Float16*)d_ws;
    _Float16* Wqkv = Xb   + (size_t)MROWS * EMB;
    _Float16* WoT  = Wqkv + (size_t)NQKV * EMB;
    _Float16* C1   = WoT  + (size_t)EMB * EMB;
    _Float16* Vt   = Wqkv;                         // reuse (after QKV GEMM)
    _Float16* Ob   = Xb;                           // reuse (after QKV GEMM)

    dim3 tb(32, 8);
    cast_x_kernel<<<MROWS * EMB / 1024, 256, 0, stream>>>(x, Xb);
    transpose_cast_qkv<<<dim3(NQKV / 32, EMB / 32), tb, 0, stream>>>(Wq, Wk, Wv, Wqkv);
    transpose_cast<<<dim3(EMB / 32, EMB / 32), tb, 0, stream>>>(Wo, WoT, EMB, EMB);

    // QKV GEMM: tiles 128x64, grid (48,32)=1536 blocks (6/CU); XCD rects 24x8
    gemm_bt<_Float16, true, 24, 8><<<dim3(NQKV / 64, MROWS / 128), 256, 0, stream>>>(
        Xb, Wqkv, C1, MROWS, NQKV, EMB, fc, fs);
    transpose_v<<<dim3(SEQ / 32, HDIM / 32, BATCH * GQA), tb, 0, stream>>>(C1, Vt);
    // attn: 512 blocks (2/CU), 4 waves each
    flash_attn<<<dim3(32, GQA * 2, BATCH), 256, 0, stream>>>(C1, Vt, Ob);
    // out-proj GEMM: tiles 128x64, grid (32,32)=1024 blocks (4/CU); XCD rects 16x8
    gemm_bt<float, false, 16, 8><<<dim3(EMB / 64, MROWS / 128), 256, 0, stream>>>(
        Ob, WoT, out, MROWS, EMB, EMB, nullptr, nullptr);
}

// Round 10
// 307.226 us; speedup vs baseline: 1.1477x; 1.1477x over previous
//
#include <hip/hip_runtime.h>
#include <stdint.h>
#include <stddef.h>

// ---------- problem constants ----------
constexpr int BATCH = 2;
constexpr int SEQ   = 2048;
constexpr int EMB   = 2048;   // DIM
constexpr int HEADS = 16;
constexpr int GQA   = 4;      // kv heads
constexpr int HDIM  = 128;
constexpr int NQKV  = 3072;   // 2048 Q + 512 K + 512 V
constexpr int VOFF  = 2560;   // column offset of V region in fused QKV
constexpr int MROWS = BATCH * SEQ;  // 4096

typedef _Float16 half8  __attribute__((ext_vector_type(8)));
typedef _Float16 half4v __attribute__((ext_vector_type(4)));
typedef float    floatx4 __attribute__((ext_vector_type(4)));

__device__ __forceinline__ void st_c(float* p, float v)    { *p = v; }
__device__ __forceinline__ void st_c(_Float16* p, float v) { *p = (_Float16)v; }

// async global->LDS, 16 B per lane, LDS dest = wave-uniform base + lane*16
__device__ __forceinline__ void gld16(const _Float16* g, _Float16* l) {
    __builtin_amdgcn_global_load_lds(
        (const __attribute__((address_space(1))) void*)g,
        (__attribute__((address_space(3))) void*)l, 16, 0, 0);
}

// ---------- 1. merged preprocessing: one launch ----------
// block ranges: [0,8192) cast x (fp32->f16, float4/thread);
// [8192,14336) Wq/Wk/Wv transpose+cast into fused Wqkv[3072][2048];
// [14336,18432) Wo transpose+cast. Branches are block-uniform; the barrier
// paths are per-block so divergent __syncthreads across ranges is safe.
__global__ __launch_bounds__(256) void preproc(const float* __restrict__ x,
                                               const float* __restrict__ Wq,
                                               const float* __restrict__ Wk,
                                               const float* __restrict__ Wv,
                                               const float* __restrict__ Wo,
                                               _Float16* __restrict__ xh,
                                               _Float16* __restrict__ wqkv,
                                               _Float16* __restrict__ wot) {
    const int bid = blockIdx.x;
    if (bid < 8192) {                       // ---- cast x ----
        int i = (bid * 256 + threadIdx.x) * 4;
        float4 v = *(const float4*)(x + i);
        half4v h;
        h[0] = (_Float16)v.x; h[1] = (_Float16)v.y; h[2] = (_Float16)v.z; h[3] = (_Float16)v.w;
        *(half4v*)(xh + i) = h;
        return;
    }
    __shared__ float tile[32][33];
    const int tx = threadIdx.x & 31, ty = threadIdx.x >> 5;   // 32 x 8
    if (bid < 8192 + 6144) {                // ---- Wqkv transpose ----
        int t  = bid - 8192;
        int cb = (t % 96) * 32, rb = (t / 96) * 32;           // cb: out-row 0..3071
        const float* src; int C, cl;
        if (cb < 2048)      { src = Wq; C = 2048; cl = cb; }
        else if (cb < 2560) { src = Wk; C = 512;  cl = cb - 2048; }
        else                { src = Wv; C = 512;  cl = cb - 2560; }
        #pragma unroll
        for (int j = 0; j < 32; j += 8)
            tile[ty + j][tx] = src[(size_t)(rb + ty + j) * C + (cl + tx)];
        __syncthreads();
        #pragma unroll
        for (int j = 0; j < 32; j += 8)
            wqkv[(size_t)(cb + ty + j) * EMB + (rb + tx)] = (_Float16)tile[tx][ty + j];
    } else {                                // ---- Wo transpose ----
        int t  = bid - 8192 - 6144;
        int cb = (t % 64) * 32, rb = (t / 64) * 32;
        #pragma unroll
        for (int j = 0; j < 32; j += 8)
            tile[ty + j][tx] = Wo[(size_t)(rb + ty + j) * EMB + (cb + tx)];
        __syncthreads();
        #pragma unroll
        for (int j = 0; j < 32; j += 8)
            wot[(size_t)(cb + ty + j) * EMB + (rb + tx)] = (_Float16)tile[tx][ty + j];
    }
}

// ---------- 3. GEMM: C[M,N] = A[M,K] * Bt[N,K]^T  (f16 in, fp32 acc) ----------
// EXACT R6/R8 configuration (measured best: qkv ~85us). GEMM exploration
// CLOSED after 9 variants spanning both axes:
//  - schedule: single-buf / double-buf / counted-vmcnt 3-buf / coarse 2-phase
//    / fine 4-phase -> all <= this (R1-R5);
//  - tiling: 256x256 & 256x192 (1 blk/CU, -20%), BK=64 (1.55 blk/CU, -19%),
//    128x64 (6 blk/CU but intensity 4.0->2.67, -28%) (R4/R5/R7/R9).
// Invariant: LDS-pipe-throughput bound; 128x128/BK=32 at 3 blk/CU maximizes
// MFMA-per-staged-byte within residency. Bank conflicts are latency-hidden
// (R7). T1 XCD rects keep FETCH at ~43MB. Do not touch.
template <typename CT, bool ROPE, int RXW, int RYH>
__global__ __launch_bounds__(256) void gemm_bt(const _Float16* __restrict__ A,
                                               const _Float16* __restrict__ Bt,
                                               CT* __restrict__ C,
                                               int M, int N, int K,
                                               const float* __restrict__ fc,
                                               const float* __restrict__ fs) {
    __shared__ _Float16 As[2][128 * 32];
    __shared__ _Float16 Bs[2][128 * 32];
    const int tid  = threadIdx.x;
    // XCD rectangle remap (grid = (2*RXW) x (4*RYH), both divisible by 8)
    const int bid = blockIdx.y * (2 * RXW) + blockIdx.x;
    const int xcd = bid & 7, loc = bid >> 3;
    const int bxi = (xcd & 1) * RXW + (loc % RXW);
    const int byi = (xcd >> 1) * RYH + (loc / RXW);
    const int bm  = byi * 128, bn = bxi * 128;
    const int lane = tid & 63, wid = tid >> 6;
    const int wr   = wid >> 1, wc = wid & 1;
    const int qd   = lane >> 4, m15 = lane & 15;

    const int srow = lane >> 2;
    const int scol = (lane & 3) * 8;
    const _Float16* Ag = A  + (size_t)(bm + wid * 16 + srow) * K + scol;
    const _Float16* Bg = Bt + (size_t)(bn + wid * 16 + srow) * K + scol;
    const size_t rowskip = (size_t)64 * K;
    const int woff = wid * 16 * 32;

    // prologue: stage tile 0 into buffer 0
    gld16(Ag,           &As[0][woff]);
    gld16(Ag + rowskip, &As[0][woff + 64 * 32]);
    gld16(Bg,           &Bs[0][woff]);
    gld16(Bg + rowskip, &Bs[0][woff + 64 * 32]);

    floatx4 acc[4][4] = {};
    const int nk = K >> 5;   // K/32 tiles

    for (int kt = 0; kt < nk; ++kt) {
        const int cur = kt & 1;
        __syncthreads();   // buf[cur] staged (vmcnt drained); prev reads of buf[cur^1] done
        if (kt + 1 < nk) { // stage tile kt+1 into the other buffer
            const int ko = (kt + 1) * 32;
            _Float16* aw = &As[cur ^ 1][woff];
            _Float16* bw = &Bs[cur ^ 1][woff];
            gld16(Ag + ko,           aw);
            gld16(Ag + rowskip + ko, aw + 64 * 32);
            gld16(Bg + ko,           bw);
            gld16(Bg + rowskip + ko, bw + 64 * 32);
        }
        const _Float16* AsR = &As[cur][(wr * 64 + m15) * 32 + qd * 8];
        const _Float16* BsR = &Bs[cur][(wc * 64 + m15) * 32 + qd * 8];
        half8 af[4], bf[4];
        #pragma unroll
        for (int i = 0; i < 4; i++) af[i] = *(const half8*)(AsR + i * 16 * 32);
        #pragma unroll
        for (int i = 0; i < 4; i++) bf[i] = *(const half8*)(BsR + i * 16 * 32);
        #pragma unroll
        for (int mi = 0; mi < 4; mi++)
            #pragma unroll
            for (int ni = 0; ni < 4; ni++)
                acc[mi][ni] = __builtin_amdgcn_mfma_f32_16x16x32_f16(af[mi], bf[ni], acc[mi][ni], 0, 0, 0);
    }

    #pragma unroll
    for (int mi = 0; mi < 4; mi++)
        #pragma unroll
        for (int ni = 0; ni < 4; ni++)
            #pragma unroll
            for (int r = 0; r < 4; r++) {
                int row = bm + wr * 64 + mi * 16 + qd * 4 + r;
                int col = bn + wc * 64 + ni * 16 + m15;
                float v = acc[mi][ni][r];
                if (ROPE && col < VOFF) {
                    int si = row & (SEQ - 1);
                    int fi = (col >> 1) & 63;
                    float c  = fc[si * 64 + fi];
                    float sn = fs[si * 64 + fi];
                    float other = __shfl_xor(v, 1, 64);
                    v = (m15 & 1) ? (v * c + other * sn) : (v * c - other * sn);
                }
                st_c(&C[(size_t)row * N + col], v);
            }
}

// ---------- 4b. V -> Vt[b][g][d][s]  (d rows 0..127) ----------
__global__ void transpose_v(const _Float16* __restrict__ qkv, _Float16* __restrict__ vt) {
    __shared__ _Float16 tile[32][33];
    int sb = blockIdx.x * 32, db = blockIdx.y * 32;
    int bg = blockIdx.z;
    int tx = threadIdx.x, ty = threadIdx.y;
    const _Float16* src = qkv + (size_t)(bg >> 2) * SEQ * NQKV + VOFF + (bg & 3) * HDIM;
    #pragma unroll
    for (int j = 0; j < 32; j += 8)
        tile[ty + j][tx] = src[(size_t)(sb + ty + j) * NQKV + db + tx];
    __syncthreads();
    _Float16* dst = vt + (size_t)bg * HDIM * SEQ;
    #pragma unroll
    for (int j = 0; j < 32; j += 8)
        dst[(size_t)(db + ty + j) * SEQ + sb + tx] = tile[tx][ty + j];
}

// ---------- 5. flash attention: 4 waves (2 heads x 2 row-halves), paired q-tiles ----------
// EXACT R8 configuration (measured win: 2 blocks/CU, -8% attn). Unchanged.
__global__ __launch_bounds__(256, 2) void flash_attn(const _Float16* __restrict__ qkv,
                                                     const _Float16* __restrict__ vt,
                                                     _Float16* __restrict__ ob) {
    const int bx   = blockIdx.x;          // 0..31
    const int g    = blockIdx.y >> 1;     // kv group
    const int hp   = blockIdx.y & 1;      // head-pair within group
    const int b    = blockIdx.z;
    const int tid  = threadIdx.x;
    const int lane = tid & 63, wid = tid >> 6;   // 4 waves
    const int h    = g * 4 + hp * 2 + (wid & 1);
    const int su   = wid >> 1;                   // 16-row half of the 32-row tile
    const int qd   = lane >> 4, m15 = lane & 15;

    __shared__ _Float16 Ks[2][64 * 128];   // [key][d], swizzled 16B chunks
    __shared__ _Float16 Vs[2][128 * 64];   // [d][key], swizzled
    __shared__ _Float16 Ps[4][16 * 64];    // per-wave P slice, swizzled

    const _Float16* kg = qkv + (size_t)(b * SEQ) * NQKV + EMB + g * HDIM;
    const _Float16* vg = vt + (size_t)(b * GQA + g) * HDIM * SEQ;
    _Float16* pw = Ps[wid];

    // staging: K 64x128 = 16 wave-instrs, V 128x64 = 16; unit t = wid*4+j
    const int kl = lane >> 4, kc16 = lane & 15;
    const int vl = lane >> 3, vc8  = lane & 7;
    const _Float16* kgp[4]; const _Float16* vgp[4];
    int ksoff[4], vsoff[4];
    #pragma unroll
    for (int j = 0; j < 4; j++) {
        int t = wid * 4 + j;
        int kr = t * 4 + kl;
        kgp[j] = kg + (size_t)kr * NQKV + ((kc16 ^ (kr & 15)) * 8);
        ksoff[j] = t * 512;
        int vr = t * 8 + vl;
        vgp[j] = vg + (size_t)vr * SEQ + ((vc8 ^ (vr & 7)) * 8);
        vsoff[j] = t * 512;
    }

    half8 ones;
    #pragma unroll
    for (int i = 0; i < 8; i++) ones[i] = (_Float16)1.0f;
    // fold 1/sqrt(128) * log2(e) into Q so p = exp2(score)
    const _Float16 qsc = (_Float16)(0.08838834764831845f * 1.44269504088896341f);

    for (int ph = 0; ph < 2; ++ph) {
        const int sidx   = ph ? bx : 63 - bx;
        const int q0     = sidx * 32;
        const int ktLast = sidx >> 1;

        __syncthreads();   // all waves done reading buffers from previous phase
        #pragma unroll
        for (int j = 0; j < 4; j++) gld16(kgp[j], &Ks[0][ksoff[j]]);
        #pragma unroll
        for (int j = 0; j < 4; j++) gld16(vgp[j], &Vs[0][vsoff[j]]);

        // Q fragments (A-operand), pre-scaled; this wave's 16 rows
        half8 qf[4];
        {
            const _Float16* qb = qkv + (size_t)(b * SEQ + q0 + su * 16 + m15) * NQKV + h * HDIM + qd * 8;
            #pragma unroll
            for (int kc = 0; kc < 4; kc++) {
                half8 q = *(const half8*)(qb + kc * 32);
                #pragma unroll
                for (int i = 0; i < 8; i++) q[i] = (_Float16)(q[i] * qsc);
                qf[kc] = q;
            }
        }

        floatx4 o[9] = {};   // [0..7]=dims, [8]=denominator

        for (int kt = 0; kt <= ktLast; ++kt) {
            const int cur = kt & 1;
            __syncthreads();    // drains vmcnt -> tile kt staged; prev reads done
            if (kt < ktLast) {  // stage tile kt+1 into other buffer
                const int nb = cur ^ 1;
                const size_t ko = (size_t)(kt + 1) * 64;
                #pragma unroll
                for (int j = 0; j < 4; j++) gld16(kgp[j] + ko * NQKV, &Ks[nb][ksoff[j]]);
                #pragma unroll
                for (int j = 0; j < 4; j++) gld16(vgp[j] + ko, &Vs[nb][vsoff[j]]);
            }
            const _Float16* ksb = Ks[cur];
            const _Float16* vsb = Vs[cur];

            // S = Q K^T
            floatx4 sa[4] = {};
            __builtin_amdgcn_s_setprio(1);
            #pragma unroll
            for (int nt = 0; nt < 4; ++nt) {
                const int kr = nt * 16 + m15;
                #pragma unroll
                for (int kc = 0; kc < 4; ++kc) {
                    half8 kf = *(const half8*)(&ksb[kr * 128 + (((kc * 4 + qd) ^ (kr & 15)) * 8)]);
                    sa[nt] = __builtin_amdgcn_mfma_f32_16x16x32_f16(qf[kc], kf, sa[nt], 0, 0, 0);
                }
            }
            __builtin_amdgcn_s_setprio(0);

            // p = exp2(s); causal mask only on the diagonal tile; write to LDS
            const bool diag = (kt == ktLast);
            const int  k0   = kt * 64;
            #pragma unroll
            for (int r = 0; r < 4; r++) {
                const int prow = qd * 4 + r;                 // local row 0..15
                const int rowg = q0 + su * 16 + prow;        // global q row
                #pragma unroll
                for (int nt = 0; nt < 4; nt++) {
                    float p = __builtin_exp2f(sa[nt][r]);
                    if (diag && (k0 + nt * 16 + m15 > rowg)) p = 0.f;
                    int chunk = (nt * 2 + (m15 >> 3)) ^ (prow & 7);
                    pw[prow * 64 + chunk * 8 + (m15 & 7)] = (_Float16)p;
                }
            }

            // P fragments back (A-operand, wave-private in-order DS)
            half8 pf[2];
            #pragma unroll
            for (int kc = 0; kc < 2; kc++)
                pf[kc] = *(const half8*)(&pw[m15 * 64 + (((kc * 4 + qd) ^ (m15 & 7)) * 8)]);

            // O += P V ; denominator via ones fragment
            __builtin_amdgcn_s_setprio(1);
            #pragma unroll
            for (int dt = 0; dt < 8; dt++) {
                const int vr = dt * 16 + m15;
                #pragma unroll
                for (int kc = 0; kc < 2; kc++) {
                    half8 vf = *(const half8*)(&vsb[vr * 64 + (((kc * 4 + qd) ^ (vr & 7)) * 8)]);
                    o[dt] = __builtin_amdgcn_mfma_f32_16x16x32_f16(pf[kc], vf, o[dt], 0, 0, 0);
                }
            }
            o[8] = __builtin_amdgcn_mfma_f32_16x16x32_f16(pf[0], ones, o[8], 0, 0, 0);
            o[8] = __builtin_amdgcn_mfma_f32_16x16x32_f16(pf[1], ones, o[8], 0, 0, 0);
            __builtin_amdgcn_s_setprio(0);
        }

        // epilogue: every lane of a row-group holds the same l in o[8][r]
        float linv[4];
        #pragma unroll
        for (int r = 0; r < 4; r++) linv[r] = 1.0f / o[8][r];
        _Float16* od = ob + (size_t)(b * SEQ + q0 + su * 16) * EMB + h * HDIM;
        #pragma unroll
        for (int dt = 0; dt < 8; dt++)
            #pragma unroll
            for (int r = 0; r < 4; r++)
                od[(size_t)(qd * 4 + r) * EMB + dt * 16 + m15] = (_Float16)(o[dt][r] * linv[r]);
    }
}

// ---------- launcher ----------
extern "C" void kernel_launch(void* const* d_in, const int* in_sizes, int n_in,
                              void* d_out, int out_size, void* d_ws, size_t ws_size,
                              hipStream_t stream) {
    (void)in_sizes; (void)n_in; (void)out_size; (void)ws_size;
    const float* x  = (const float*)d_in[0];
    const float* fc = (const float*)d_in[1];
    const float* fs = (const float*)d_in[2];
    const float* Wq = (const float*)d_in[3];
    const float* Wk = (const float*)d_in[4];
    const float* Wv = (const float*)d_in[5];
    const float* Wo = (const float*)d_in[6];
    float* out = (float*)d_out;

    // workspace layout (f16), 60 MB
    _Float16* Xb   = (_Float16*)d_ws;
    _Float16* Wqkv = Xb   + (size_t)MROWS * EMB;
    _Float16* WoT  = Wqkv + (size_t)NQKV * EMB;
    _Float16* C1   = WoT  + (size_t)EMB * EMB;
    _Float16* Vt   = Wqkv;                         // reuse (after QKV GEMM)
    _Float16* Ob   = Xb;                           // reuse (after QKV GEMM)

    dim3 tb(32, 8);
    // merged preproc: 8192 (cast x) + 6144 (Wqkv^T) + 4096 (Wo^T) blocks
    preproc<<<18432, 256, 0, stream>>>(x, Wq, Wk, Wv, Wo, Xb, Wqkv, WoT);

    // QKV GEMM: grid (24,32)=768 blocks; XCD rects 12x8
    gemm_bt<_Float16, true, 12, 8><<<dim3(NQKV / 128, MROWS / 128), 256, 0, stream>>>(
        Xb, Wqkv, C1, MROWS, NQKV, EMB, fc, fs);
    transpose_v<<<dim3(SEQ / 32, HDIM / 32, BATCH * GQA), tb, 0, stream>>>(C1, Vt);
    // attn: 512 blocks (2/CU), 4 waves each
    flash_attn<<<dim3(32, GQA * 2, BATCH), 256, 0, stream>>>(C1, Vt, Ob);
    // out-proj GEMM: grid (16,32)=512 blocks; XCD rects 8x8
    gemm_bt<float, false, 8, 8><<<dim3(EMB / 128, MROWS / 128), 256, 0, stream>>>(
        Ob, WoT, out, MROWS, EMB, EMB, nullptr, nullptr);
}